// Round 15
// baseline (192.910 us; speedup 1.0000x reference)
//
#include <hip/hip_runtime.h>
#include <cstdint>

#define T_TOK 4096
#define HID 2048
#define NH 16
#define NKV 4
#define HD 128
#define WIN 1024
#define QKVO 3072

typedef float f32x4 __attribute__((ext_vector_type(4)));
typedef float f32x16 __attribute__((ext_vector_type(16)));
typedef __bf16 bf16x8 __attribute__((ext_vector_type(8)));
typedef __bf16 bf16x4 __attribute__((ext_vector_type(4)));
typedef unsigned int u32x4 __attribute__((ext_vector_type(4)));

__device__ __forceinline__ void gload16(const void* g, void* lds) {
  auto gp = reinterpret_cast<__attribute__((address_space(1))) void*>(
      reinterpret_cast<uintptr_t>(g));
  auto lp = reinterpret_cast<__attribute__((address_space(3))) void*>(
      reinterpret_cast<uintptr_t>(lds));
  __builtin_amdgcn_global_load_lds(gp, lp, 16, 0, 0);
}

__device__ __forceinline__ f32x4 mfma16(bf16x8 a, bf16x8 b, f32x4 c) {
  return __builtin_amdgcn_mfma_f32_16x16x32_bf16(a, b, c, 0, 0, 0);
}
__device__ __forceinline__ f32x16 mfma32(bf16x8 a, bf16x8 b, f32x16 c) {
  return __builtin_amdgcn_mfma_f32_32x32x16_bf16(a, b, c, 0, 0, 0);
}
__device__ __forceinline__ unsigned cvtpk(float lo, float hi) {
  unsigned r;
  asm("v_cvt_pk_bf16_f32 %0, %1, %2" : "=v"(r) : "v"(lo), "v"(hi));
  return r;
}
// swaps a[lanes 32:63] <-> b[lanes 0:31]; after: a={a.lo,b.lo}, b={a.hi,b.hi}
__device__ __forceinline__ void pl32swap(unsigned& a, unsigned& b) {
  asm volatile("v_permlane32_swap_b32 %0, %1" : "+v"(a), "+v"(b));
}

// ---------------- fp32 -> bf16 elementwise (hidden) ----------------
__global__ __launch_bounds__(256) void k_f32_to_bf16(const float* __restrict__ x,
                                                     __bf16* __restrict__ y) {
  const size_t e = (size_t)blockIdx.x * 256 + threadIdx.x;  // 8 elems each
  const float4* xv = (const float4*)x;
  float4 a = xv[e * 2], b = xv[e * 2 + 1];
  bf16x8 o;
  o[0] = (__bf16)a.x; o[1] = (__bf16)a.y; o[2] = (__bf16)a.z; o[3] = (__bf16)a.w;
  o[4] = (__bf16)b.x; o[5] = (__bf16)b.y; o[6] = (__bf16)b.z; o[7] = (__bf16)b.w;
  *(bf16x8*)(y + e * 8) = o;
}

// ---------------- merged fp32->bf16 transpose of BOTH weights ----------------
__global__ __launch_bounds__(256) void k_transpose2(
    const float* __restrict__ W1, __bf16* __restrict__ Wt1,
    const float* __restrict__ W2, __bf16* __restrict__ Wt2) {
  __shared__ float lt[64][69];
  int bid = blockIdx.x;
  const float* W;
  __bf16* Wt;
  int R, C;
  if (bid < 1536) {
    W = W1; Wt = Wt1; R = HID; C = QKVO;
  } else {
    bid -= 1536; W = W2; Wt = Wt2; R = HID; C = HID;
  }
  const int nbx = C >> 6;
  const int c0 = (bid % nbx) << 6;
  const int r0 = (bid / nbx) << 6;
  const int tid = threadIdx.x;
  const int tx = tid & 15, ty = tid >> 4;
#pragma unroll
  for (int i = 0; i < 4; i++) {
    const int r = ty + 16 * i;
    const float4 v = *(const float4*)(W + (size_t)(r0 + r) * C + c0 + 4 * tx);
    lt[r][4 * tx] = v.x;
    lt[r][4 * tx + 1] = v.y;
    lt[r][4 * tx + 2] = v.z;
    lt[r][4 * tx + 3] = v.w;
  }
  __syncthreads();
  const int ux = tid & 7, uy = tid >> 3;
#pragma unroll
  for (int i = 0; i < 2; i++) {
    const int c = uy + 32 * i;
    bf16x8 o;
#pragma unroll
    for (int k = 0; k < 8; k++) o[k] = (__bf16)lt[8 * ux + k][c];
    *(bf16x8*)(Wt + (size_t)(c0 + c) * R + r0 + 8 * ux) = o;
  }
}

// ---------------- RoPE cos/sin tables ----------------
__global__ void k_rope_tab(const int* __restrict__ pos, float* __restrict__ cosT,
                           float* __restrict__ sinT) {
  const int t = blockIdx.x;
  const int d = threadIdx.x;  // 0..63
  const float inv = exp2f(-(float)d * (16.609640474436812f / 64.0f));  // theta^-d/64
  const float fr = (float)pos[t] * inv;
  cosT[t * 64 + d] = cosf(fr);
  sinT[t * 64 + d] = sinf(fr);
}

// ---------------- 128x128-tile bf16 GEMM, v5 ----------------
// MODE 0: C[M][N] fp32, no bias (out-proj).
// MODE 1: fused QKV: bias + RoPE epilogue. Q -> Qp row-major (scaled);
//   K -> Kf A-FRAGMENT-packed (RoPE'd in-place in LDS, then packed);
//   V -> Vf A-fragment-packed. Attn then needs NO LDS at all.
template <int MODE>
__global__ __launch_bounds__(256, 2) void k_gemm(
    const __bf16* __restrict__ A, const __bf16* __restrict__ Bt,
    const float* __restrict__ bias, float* __restrict__ C,
    const float* __restrict__ cosT, const float* __restrict__ sinT,
    __bf16* __restrict__ Qp, __bf16* __restrict__ Kf, __bf16* __restrict__ Vf,
    int M, int N, int K) {
  __shared__ __align__(16) __bf16 smem[32768];  // 64KB: As|Bs dbuf; epi reuse
  const int tid = threadIdx.x;
  const int lane = tid & 63;
  const int w = tid >> 6;
  const int wr = w >> 1, wc = w & 1;
  const int c = lane & 15, g = lane >> 4;
  const int csw = (c & 7) << 4;  // read-side XOR key (row&7 == c&7)

  // XCD supertile remap (bijective: grid = 8 XCDs * spx supertiles * 16 blocks)
  const int nstc = N >> 9;
  const int bid = blockIdx.x;
  const int xcd = bid & 7;
  const int j = bid >> 3;
  const int spx = (int)(gridDim.x >> 7);
  const int s = xcd * spx + (j >> 4);
  const int q = j & 15;
  const int by = (s / nstc) * 4 + (q >> 2);
  const int bx = (s % nstc) * 4 + (q & 3);
  const int m0 = by << 7, n0 = bx << 7;

  const int o0 = w * 4096 + lane * 16;
  const int srow = 32 * w + (lane >> 3);
  const int schunk = (lane & 7) ^ ((lane >> 3) & 7);
  const __bf16* gA0 = A + (size_t)(m0 + srow) * K + schunk * 8;
  const __bf16* gB0 = Bt + (size_t)(n0 + srow) * K + schunk * 8;

  f32x4 acc[4][4] = {};

  {
    char* la = (char*)smem;
    char* lb = (char*)smem + 32768;
#pragma unroll
    for (int qq = 0; qq < 4; qq++) {
      gload16(gA0 + (size_t)qq * 8 * K, la + o0 + qq * 1024);
      gload16(gB0 + (size_t)qq * 8 * K, lb + o0 + qq * 1024);
    }
  }
  __syncthreads();

  int cur = 0;
  for (int kt = 0; kt < K; kt += 64) {
    if (kt + 64 < K) {
      char* la = (char*)smem + (cur ^ 1) * 16384;
      char* lb = (char*)smem + 32768 + (cur ^ 1) * 16384;
#pragma unroll
      for (int qq = 0; qq < 4; qq++) {
        gload16(gA0 + kt + 64 + (size_t)qq * 8 * K, la + o0 + qq * 1024);
        gload16(gB0 + kt + 64 + (size_t)qq * 8 * K, lb + o0 + qq * 1024);
      }
    }
    const char* as = (const char*)smem + cur * 16384;
    const char* bs = (const char*)smem + 32768 + cur * 16384;
#pragma unroll
    for (int ds = 0; ds < 2; ds++) {
      bf16x8 af[4], bfr[4];
#pragma unroll
      for (int mi = 0; mi < 4; mi++)
        af[mi] = *(const bf16x8*)(as + (wr * 64 + mi * 16 + c) * 128 +
                                  ((ds * 64 + g * 16) ^ csw));
#pragma unroll
      for (int ni = 0; ni < 4; ni++)
        bfr[ni] = *(const bf16x8*)(bs + (wc * 64 + ni * 16 + c) * 128 +
                                   ((ds * 64 + g * 16) ^ csw));
#pragma unroll
      for (int mi = 0; mi < 4; mi++)
#pragma unroll
        for (int ni = 0; ni < 4; ni++)
          acc[mi][ni] = mfma16(af[mi], bfr[ni], acc[mi][ni]);
    }
    __syncthreads();
    cur ^= 1;
  }

  if constexpr (MODE == 0) {
#pragma unroll
    for (int ni = 0; ni < 4; ni++) {
      const int col = n0 + wc * 64 + ni * 16 + c;
#pragma unroll
      for (int mi = 0; mi < 4; mi++)
#pragma unroll
        for (int r = 0; r < 4; r++) {
          const int row = m0 + wr * 64 + mi * 16 + 4 * g + r;
          C[(size_t)row * N + col] = acc[mi][ni][r];
        }
    }
  } else {
    // ---- fused epilogue: acc+bias -> LDS bf16 [128][136]
    __bf16* sm = smem;
#pragma unroll
    for (int ni = 0; ni < 4; ni++) {
      const int col = wc * 64 + ni * 16 + c;
      const float bv = bias[n0 + col];
#pragma unroll
      for (int mi = 0; mi < 4; mi++)
#pragma unroll
        for (int r = 0; r < 4; r++)
          sm[(wr * 64 + mi * 16 + 4 * g + r) * 136 + col] =
              (__bf16)(acc[mi][ni][r] + bv);
    }
    __syncthreads();

    if (n0 < NH * HD) {  // Q head: RoPE, scale*log2e folded, row-major out
      const float sc = 0.08838834764831845f * 1.4426950408889634f;
      __bf16* base = Qp + (size_t)(n0 >> 7) * T_TOK * HD;
#pragma unroll
      for (int jj = 0; jj < 4; jj++) {
        const int e = jj * 256 + tid;  // 128 t x 8 chunks of 8
        const int tl = e >> 3, ch = e & 7;
        const int tt = m0 + tl;
        const bf16x8 x1 = *(const bf16x8*)(sm + tl * 136 + ch * 8);
        const bf16x8 x2 = *(const bf16x8*)(sm + tl * 136 + 64 + ch * 8);
        const float4 c0 = *(const float4*)(cosT + tt * 64 + ch * 8);
        const float4 c1 = *(const float4*)(cosT + tt * 64 + ch * 8 + 4);
        const float4 s0 = *(const float4*)(sinT + tt * 64 + ch * 8);
        const float4 s1 = *(const float4*)(sinT + tt * 64 + ch * 8 + 4);
        const float cs[8] = {c0.x, c0.y, c0.z, c0.w, c1.x, c1.y, c1.z, c1.w};
        const float sn[8] = {s0.x, s0.y, s0.z, s0.w, s1.x, s1.y, s1.z, s1.w};
        bf16x8 o1, o2;
#pragma unroll
        for (int i = 0; i < 8; i++) {
          const float a = (float)x1[i], b = (float)x2[i];
          o1[i] = (__bf16)((a * cs[i] - b * sn[i]) * sc);
          o2[i] = (__bf16)((b * cs[i] + a * sn[i]) * sc);
        }
        __bf16* dst = base + (size_t)tt * HD;
        *(bf16x8*)(dst + ch * 8) = o1;
        *(bf16x8*)(dst + 64 + ch * 8) = o2;
      }
    } else if (n0 < (NH + NKV) * HD) {  // K head: RoPE in place, then frag-pack
      // (1) RoPE in place: each (tl,ch) slot read+written by exactly one thread
#pragma unroll
      for (int jj = 0; jj < 4; jj++) {
        const int e = jj * 256 + tid;
        const int tl = e >> 3, ch = e & 7;
        const int tt = m0 + tl;
        const bf16x8 x1 = *(const bf16x8*)(sm + tl * 136 + ch * 8);
        const bf16x8 x2 = *(const bf16x8*)(sm + tl * 136 + 64 + ch * 8);
        const float4 c0 = *(const float4*)(cosT + tt * 64 + ch * 8);
        const float4 c1 = *(const float4*)(cosT + tt * 64 + ch * 8 + 4);
        const float4 s0 = *(const float4*)(sinT + tt * 64 + ch * 8);
        const float4 s1 = *(const float4*)(sinT + tt * 64 + ch * 8 + 4);
        const float cs[8] = {c0.x, c0.y, c0.z, c0.w, c1.x, c1.y, c1.z, c1.w};
        const float sn[8] = {s0.x, s0.y, s0.z, s0.w, s1.x, s1.y, s1.z, s1.w};
        bf16x8 o1, o2;
#pragma unroll
        for (int i = 0; i < 8; i++) {
          const float a = (float)x1[i], b = (float)x2[i];
          o1[i] = (__bf16)(a * cs[i] - b * sn[i]);
          o2[i] = (__bf16)(b * cs[i] + a * sn[i]);
        }
        *(bf16x8*)(sm + tl * 136 + ch * 8) = o1;
        *(bf16x8*)(sm + tl * 136 + 64 + ch * 8) = o2;
      }
      __syncthreads();
      // (2) pack 2 x 64-key tiles in A-fragment order:
      // unit un = t2*8+ds; elem j of (un,lu) = K[st2*64 + t2*32 + (lu&31)]
      //                                        [ds*16 + (lu>>5)*8 + j]
      const int kvidx = (n0 >> 7) - NH;
#pragma unroll
      for (int st2 = 0; st2 < 2; st2++) {
        __bf16* outb = Kf + ((size_t)kvidx * 64 + (m0 >> 6) + st2) * 8192;
#pragma unroll
        for (int jj = 0; jj < 4; jj++) {
          const int u = jj * 256 + tid;  // 16 units x 64 lanes
          const int lu = u & 63, un = u >> 6;
          const int t2 = un >> 3, ds = un & 7;
          const int row = st2 * 64 + t2 * 32 + (lu & 31);
          const int kcol = ds * 16 + ((lu >> 5) << 3);
          const bf16x8 o = *(const bf16x8*)(sm + row * 136 + kcol);
          *(bf16x8*)(outb + (size_t)u * 8) = o;
        }
      }
    } else {  // V head: fragment-pack two 64-token subtiles
      const int kv = (n0 >> 7) - (NH + NKV);
#pragma unroll
      for (int st2 = 0; st2 < 2; st2++) {
        __bf16* outb = Vf + ((size_t)kv * 64 + (m0 >> 6) + st2) * 8192;
#pragma unroll
        for (int jj = 0; jj < 4; jj++) {
          const int u = jj * 256 + tid;
          const int lu = u & 63, ks = (u >> 6) & 3, mq = u >> 8;
          const int d = mq * 32 + (lu & 31);
          const int tb = st2 * 64 + ks * 16 + ((lu >> 5) << 3);
          bf16x8 o;
#pragma unroll
          for (int jz = 0; jz < 8; jz++) o[jz] = sm[(tb + jz) * 136 + d];
          *(bf16x8*)(outb + (size_t)u * 8) = o;
        }
      }
    }
  }
}

// ---------------- flash attention v12: ZERO LDS, ZERO barriers ----------------
// K and V both A-fragment-packed in global (L2-resident via kvh->XCD map).
// Waves fully independent: each iterates only its own relevant tile range.
// Per tile: 32 coalesced 1KB loads (16 K-frag + 16 V-frag) issued up front,
// QK^T covers K latency, softmax+QK cover V latency. In-reg P (T12), T13.
__global__ __launch_bounds__(256, 2) void k_attn(const __bf16* __restrict__ Qp,
                                                 const __bf16* __restrict__ Kf,
                                                 const __bf16* __restrict__ Vf,
                                                 __bf16* __restrict__ attnO) {
  const int tid = threadIdx.x;
  const int lane = tid & 63;
  const int w = tid >> 6;      // 0..3
  const int l31 = lane & 31;
  const int hi = lane >> 5;    // 0/1
  // bijective decode: xcd = bid&7 hosts heads {4*(xcd>>1) + 2*(xcd&1) + 0/1}
  const int bid = blockIdx.x;
  const int xcd = bid & 7, j = bid >> 3;
  const int h = ((xcd >> 1) << 2) + ((xcd & 1) << 1) + (j & 1);
  const int qb = 31 - (j >> 1);  // heavy blocks first
  const int kvh = h >> 2;
  const int q0 = qb * 128;
  const int iw = q0 + 32 * w;       // wave's first q row
  const int irow = iw + l31;        // this lane's q row

  // Q B-frags: col=q(=l31), k-step ds covers d=16ds+8hi+j
  bf16x8 qf[8];
  {
    const __bf16* qbase = Qp + ((size_t)h * T_TOK + irow) * HD;
#pragma unroll
    for (int ds = 0; ds < 8; ds++)
      qf[ds] = *(const bf16x8*)(qbase + ds * 16 + hi * 8);
  }

  f32x16 ot[4] = {};  // O^T: ot[m][reg] -> d=32m+(reg&3)+8*(reg>>2)+4hi, q=l31
  float mrun = 0.0f, lrun = 0.0f;  // exp2-domain, max-floor 0

  // wave-private tile range: keys max(0, iw-WIN) .. iw+31
  const int t0i = (iw >= WIN) ? ((iw - WIN) >> 6) : 0;
  const int t1i = (iw + 31) >> 6;  // inclusive
  const __bf16* Kgb = Kf + (size_t)kvh * 64 * 8192;
  const __bf16* Vgb = Vf + (size_t)kvh * 64 * 8192;

  for (int tt = t0i; tt <= t1i; ++tt) {
    const int j0 = tt * 64;
    const __bf16* kt = Kgb + (size_t)tt * 8192;
    const __bf16* vt = Vgb + (size_t)tt * 8192;

    // ---- issue all fragment loads up front (coalesced 1KB each)
    bf16x8 kfA[8], kfB[8];
#pragma unroll
    for (int ds = 0; ds < 8; ds++)
      kfA[ds] = *(const bf16x8*)(kt + (size_t)(ds * 64 + lane) * 8);
#pragma unroll
    for (int ds = 0; ds < 8; ds++)
      kfB[ds] = *(const bf16x8*)(kt + (size_t)((8 + ds) * 64 + lane) * 8);
    bf16x8 vf[4][4];
#pragma unroll
    for (int m = 0; m < 4; m++)
#pragma unroll
      for (int ks = 0; ks < 4; ks++)
        vf[m][ks] = *(const bf16x8*)(vt + (size_t)(m * 256 + ks * 64 + lane) * 8);

    // ---- S^T = K * Q^T : 2 key-subtiles x 8 k-steps of 32x32x16
    f32x16 st[2] = {};
    __builtin_amdgcn_s_setprio(1);
#pragma unroll
    for (int ds = 0; ds < 8; ds++) st[0] = mfma32(kfA[ds], qf[ds], st[0]);
#pragma unroll
    for (int ds = 0; ds < 8; ds++) st[1] = mfma32(kfB[ds], qf[ds], st[1]);
    __builtin_amdgcn_s_setprio(0);

    // ---- mask + online softmax; q=l31 lane-local.
    // key j = j0 + 32t + (reg&3) + 8*(reg>>2) + 4*hi
    float p[2][16];
    float cmax = -1e30f;
    const bool interior = (j0 + 63 <= iw) && (iw + 31 - j0 <= WIN);
    if (interior) {
#pragma unroll
      for (int t = 0; t < 2; t++)
#pragma unroll
        for (int r = 0; r < 16; r++) {
          const float s = st[t][r];
          p[t][r] = s;
          cmax = fmaxf(cmax, s);
        }
    } else {
      const int jb = irow - j0 - 4 * hi;  // i-j = jb - 32t - (r&3) - 8*(r>>2)
#pragma unroll
      for (int t = 0; t < 2; t++)
#pragma unroll
        for (int r = 0; r < 16; r++) {
          float s = st[t][r];
          const int off = 32 * t + (r & 3) + 8 * (r >> 2);
          s = ((unsigned)(jb - off) <= WIN) ? s : -1e30f;
          p[t][r] = s;
          cmax = fmaxf(cmax, s);
        }
    }
    cmax = fmaxf(cmax, __shfl_xor(cmax, 32));  // partner holds other keys

    // defer-max (T13): THR = 8*log2e
    if (!__all(cmax <= mrun + 11.54f)) {
      const float mn = fmaxf(mrun, cmax);
      const float alpha = exp2f(mrun - mn);
      lrun *= alpha;
#pragma unroll
      for (int m = 0; m < 4; m++) ot[m] *= alpha;
      mrun = mn;
    }
    float rs = 0.0f;
#pragma unroll
    for (int t = 0; t < 2; t++)
#pragma unroll
      for (int r = 0; r < 16; r++) {
        const float e_ = exp2f(p[t][r] - mrun);
        p[t][r] = e_;
        rs += e_;
      }
    rs += __shfl_xor(rs, 32);
    lrun += rs;

    // ---- P -> PV B-frags in-register (cvt_pk + permlane32_swap, T12)
    bf16x8 pb[4];
#pragma unroll
    for (int t = 0; t < 2; t++) {
      unsigned wds[8];
#pragma unroll
      for (int i = 0; i < 8; i++) wds[i] = cvtpk(p[t][2 * i], p[t][2 * i + 1]);
      pl32swap(wds[0], wds[2]);
      pl32swap(wds[1], wds[3]);
      pl32swap(wds[4], wds[6]);
      pl32swap(wds[5], wds[7]);
      u32x4 f0 = {wds[0], wds[1], wds[2], wds[3]};
      u32x4 f1 = {wds[4], wds[5], wds[6], wds[7]};
      pb[2 * t] = __builtin_bit_cast(bf16x8, f0);
      pb[2 * t + 1] = __builtin_bit_cast(bf16x8, f1);
    }

    // ---- O^T += V^T * P^T : 4 d-subtiles x 4 key-steps of 32x32x16
    __builtin_amdgcn_s_setprio(1);
#pragma unroll
    for (int m = 0; m < 4; m++)
#pragma unroll
      for (int ks = 0; ks < 4; ks++)
        ot[m] = mfma32(vf[m][ks], pb[ks], ot[m]);
    __builtin_amdgcn_s_setprio(0);
  }

  const float inv_l = 1.0f / lrun;
  __bf16* orow = attnO + (size_t)irow * (NH * HD) + h * HD;
#pragma unroll
  for (int m = 0; m < 4; m++)
#pragma unroll
    for (int rg = 0; rg < 4; rg++) {
      const int d0 = 32 * m + 8 * rg + 4 * hi;
      bf16x4 o4;
#pragma unroll
      for (int r = 0; r < 4; r++) o4[r] = (__bf16)(ot[m][4 * rg + r] * inv_l);
      *(bf16x4*)(orow + d0) = o4;
    }
}

// ---------------- launcher ----------------
extern "C" void kernel_launch(void* const* d_in, const int* in_sizes, int n_in,
                              void* d_out, int out_size, void* d_ws, size_t ws_size,
                              hipStream_t stream) {
  (void)in_sizes; (void)n_in; (void)out_size; (void)ws_size;
  const float* hidden = (const float*)d_in[0];
  const int* positions = (const int*)d_in[1];
  const float* w_qkv = (const float*)d_in[2];
  const float* b_qkv = (const float*)d_in[3];
  const float* w_o = (const float*)d_in[4];
  float* out = (float*)d_out;

  char* ws = (char*)d_ws;
  __bf16* Hb = (__bf16*)ws;    ws += (size_t)T_TOK * HID * 2;
  __bf16* Wqkvt = (__bf16*)ws; ws += (size_t)QKVO * HID * 2;
  __bf16* Wot = (__bf16*)ws;   ws += (size_t)HID * HID * 2;
  float* cosT = (float*)ws;    ws += (size_t)T_TOK * 64 * 4;
  float* sinT = (float*)ws;    ws += (size_t)T_TOK * 64 * 4;
  __bf16* Qp = (__bf16*)ws;    ws += (size_t)NH * T_TOK * HD * 2;
  __bf16* Kfb = (__bf16*)ws;   ws += (size_t)NKV * 64 * 8192 * 2;   // frag-packed K
  __bf16* Vfb = (__bf16*)ws;   ws += (size_t)NKV * 64 * 8192 * 2;   // frag-packed V
  __bf16* attnb = (__bf16*)ws; ws += (size_t)T_TOK * NH * HD * 2;

  k_f32_to_bf16<<<T_TOK * HID / (256 * 8), 256, 0, stream>>>(hidden, Hb);
  k_transpose2<<<2560, 256, 0, stream>>>(w_qkv, Wqkvt, w_o, Wot);
  k_rope_tab<<<T_TOK, 64, 0, stream>>>(positions, cosT, sinT);
  k_gemm<1><<<(T_TOK / 128) * (QKVO / 128), 256, 0, stream>>>(
      Hb, Wqkvt, b_qkv, nullptr, cosT, sinT, Qp, Kfb, Vfb, T_TOK, QKVO, HID);
  k_attn<<<512, 256, 0, stream>>>(Qp, Kfb, Vfb, attnb);
  k_gemm<0><<<(T_TOK / 128) * (HID / 128), 256, 0, stream>>>(
      attnb, Wot, nullptr, out, nullptr, nullptr, nullptr, nullptr, nullptr,
      T_TOK, HID, HID);
}

// Round 16
// 166.400 us; speedup vs baseline: 1.1593x; 1.1593x over previous
//
#include <hip/hip_runtime.h>
#include <cstdint>

#define T_TOK 4096
#define HID 2048
#define NH 16
#define NKV 4
#define HD 128
#define WIN 1024
#define QKVO 3072

typedef float f32x4 __attribute__((ext_vector_type(4)));
typedef float f32x16 __attribute__((ext_vector_type(16)));
typedef __bf16 bf16x8 __attribute__((ext_vector_type(8)));
typedef __bf16 bf16x4 __attribute__((ext_vector_type(4)));
typedef unsigned int u32x4 __attribute__((ext_vector_type(4)));

__device__ __forceinline__ void gload16(const void* g, void* lds) {
  auto gp = reinterpret_cast<__attribute__((address_space(1))) void*>(
      reinterpret_cast<uintptr_t>(g));
  auto lp = reinterpret_cast<__attribute__((address_space(3))) void*>(
      reinterpret_cast<uintptr_t>(lds));
  __builtin_amdgcn_global_load_lds(gp, lp, 16, 0, 0);
}

__device__ __forceinline__ f32x4 mfma16(bf16x8 a, bf16x8 b, f32x4 c) {
  return __builtin_amdgcn_mfma_f32_16x16x32_bf16(a, b, c, 0, 0, 0);
}
__device__ __forceinline__ f32x16 mfma32(bf16x8 a, bf16x8 b, f32x16 c) {
  return __builtin_amdgcn_mfma_f32_32x32x16_bf16(a, b, c, 0, 0, 0);
}
__device__ __forceinline__ unsigned cvtpk(float lo, float hi) {
  unsigned r;
  asm("v_cvt_pk_bf16_f32 %0, %1, %2" : "=v"(r) : "v"(lo), "v"(hi));
  return r;
}
// swaps a[lanes 32:63] <-> b[lanes 0:31]; after: a={a.lo,b.lo}, b={a.hi,b.hi}
__device__ __forceinline__ void pl32swap(unsigned& a, unsigned& b) {
  asm volatile("v_permlane32_swap_b32 %0, %1" : "+v"(a), "+v"(b));
}

// ---------------- merged prep: hidden f32->bf16 | weight transposes | tables
// blocks [0,4096): hidden -> Hb (bf16), 2048 elems/block
// blocks [4096,6656): 64x64 transpose tiles (w_qkv then w_o), fp32->bf16
// blocks [6656,7680): rope cos/sin tables (one (t,d) per thread)
__global__ __launch_bounds__(256) void k_prep(
    const float* __restrict__ hidden, __bf16* __restrict__ Hb,
    const float* __restrict__ W1, __bf16* __restrict__ Wt1,
    const float* __restrict__ W2, __bf16* __restrict__ Wt2,
    const int* __restrict__ pos, float* __restrict__ cosT,
    float* __restrict__ sinT) {
  const int tid = threadIdx.x;
  int bid = blockIdx.x;
  if (bid < 4096) {  // f32 -> bf16
    const size_t e = (size_t)bid * 256 + tid;  // 8 elems each
    const float4* xv = (const float4*)hidden;
    float4 a = xv[e * 2], b = xv[e * 2 + 1];
    bf16x8 o;
    o[0] = (__bf16)a.x; o[1] = (__bf16)a.y; o[2] = (__bf16)a.z; o[3] = (__bf16)a.w;
    o[4] = (__bf16)b.x; o[5] = (__bf16)b.y; o[6] = (__bf16)b.z; o[7] = (__bf16)b.w;
    *(bf16x8*)(Hb + e * 8) = o;
    return;
  }
  if (bid >= 6656) {  // rope tables
    const int e = (bid - 6656) * 256 + tid;
    const int t = e >> 6, d = e & 63;
    const float inv = exp2f(-(float)d * (16.609640474436812f / 64.0f));
    const float fr = (float)pos[t] * inv;
    cosT[t * 64 + d] = cosf(fr);
    sinT[t * 64 + d] = sinf(fr);
    return;
  }
  // transpose tiles
  __shared__ float lt[64][69];
  bid -= 4096;
  const float* W;
  __bf16* Wt;
  int R, C;
  if (bid < 1536) {
    W = W1; Wt = Wt1; R = HID; C = QKVO;
  } else {
    bid -= 1536; W = W2; Wt = Wt2; R = HID; C = HID;
  }
  const int nbx = C >> 6;
  const int c0 = (bid % nbx) << 6;
  const int r0 = (bid / nbx) << 6;
  const int tx = tid & 15, ty = tid >> 4;
#pragma unroll
  for (int i = 0; i < 4; i++) {
    const int r = ty + 16 * i;
    const float4 v = *(const float4*)(W + (size_t)(r0 + r) * C + c0 + 4 * tx);
    lt[r][4 * tx] = v.x;
    lt[r][4 * tx + 1] = v.y;
    lt[r][4 * tx + 2] = v.z;
    lt[r][4 * tx + 3] = v.w;
  }
  __syncthreads();
  const int ux = tid & 7, uy = tid >> 3;
#pragma unroll
  for (int i = 0; i < 2; i++) {
    const int c = uy + 32 * i;
    bf16x8 o;
#pragma unroll
    for (int k = 0; k < 8; k++) o[k] = (__bf16)lt[8 * ux + k][c];
    *(bf16x8*)(Wt + (size_t)(c0 + c) * R + r0 + 8 * ux) = o;
  }
}

// ---------------- 128x128-tile bf16 GEMM, v4 (R14 verbatim) ----------------
// MODE 0: C[M][N] fp32, no bias (out-proj).
// MODE 1: fused QKV: bias + RoPE/pack epilogue writing Qp/Kp/Vf directly.
template <int MODE>
__global__ __launch_bounds__(256, 2) void k_gemm(
    const __bf16* __restrict__ A, const __bf16* __restrict__ Bt,
    const float* __restrict__ bias, float* __restrict__ C,
    const float* __restrict__ cosT, const float* __restrict__ sinT,
    __bf16* __restrict__ Qp, __bf16* __restrict__ Kp, __bf16* __restrict__ Vf,
    int M, int N, int K) {
  __shared__ __align__(16) __bf16 smem[32768];  // 64KB: As|Bs dbuf; epi reuse
  const int tid = threadIdx.x;
  const int lane = tid & 63;
  const int w = tid >> 6;
  const int wr = w >> 1, wc = w & 1;
  const int c = lane & 15, g = lane >> 4;
  const int csw = (c & 7) << 4;  // read-side XOR key (row&7 == c&7)

  // XCD supertile remap (bijective: grid = 8 XCDs * spx supertiles * 16 blocks)
  const int nstc = N >> 9;
  const int bid = blockIdx.x;
  const int xcd = bid & 7;
  const int j = bid >> 3;
  const int spx = (int)(gridDim.x >> 7);
  const int s = xcd * spx + (j >> 4);
  const int q = j & 15;
  const int by = (s / nstc) * 4 + (q >> 2);
  const int bx = (s % nstc) * 4 + (q & 3);
  const int m0 = by << 7, n0 = bx << 7;

  const int o0 = w * 4096 + lane * 16;
  const int srow = 32 * w + (lane >> 3);
  const int schunk = (lane & 7) ^ ((lane >> 3) & 7);
  const __bf16* gA0 = A + (size_t)(m0 + srow) * K + schunk * 8;
  const __bf16* gB0 = Bt + (size_t)(n0 + srow) * K + schunk * 8;

  f32x4 acc[4][4] = {};

  {
    char* la = (char*)smem;
    char* lb = (char*)smem + 32768;
#pragma unroll
    for (int qq = 0; qq < 4; qq++) {
      gload16(gA0 + (size_t)qq * 8 * K, la + o0 + qq * 1024);
      gload16(gB0 + (size_t)qq * 8 * K, lb + o0 + qq * 1024);
    }
  }
  __syncthreads();

  int cur = 0;
  for (int kt = 0; kt < K; kt += 64) {
    if (kt + 64 < K) {
      char* la = (char*)smem + (cur ^ 1) * 16384;
      char* lb = (char*)smem + 32768 + (cur ^ 1) * 16384;
#pragma unroll
      for (int qq = 0; qq < 4; qq++) {
        gload16(gA0 + kt + 64 + (size_t)qq * 8 * K, la + o0 + qq * 1024);
        gload16(gB0 + kt + 64 + (size_t)qq * 8 * K, lb + o0 + qq * 1024);
      }
    }
    const char* as = (const char*)smem + cur * 16384;
    const char* bs = (const char*)smem + 32768 + cur * 16384;
#pragma unroll
    for (int ds = 0; ds < 2; ds++) {
      bf16x8 af[4], bfr[4];
#pragma unroll
      for (int mi = 0; mi < 4; mi++)
        af[mi] = *(const bf16x8*)(as + (wr * 64 + mi * 16 + c) * 128 +
                                  ((ds * 64 + g * 16) ^ csw));
#pragma unroll
      for (int ni = 0; ni < 4; ni++)
        bfr[ni] = *(const bf16x8*)(bs + (wc * 64 + ni * 16 + c) * 128 +
                                   ((ds * 64 + g * 16) ^ csw));
#pragma unroll
      for (int mi = 0; mi < 4; mi++)
#pragma unroll
        for (int ni = 0; ni < 4; ni++)
          acc[mi][ni] = mfma16(af[mi], bfr[ni], acc[mi][ni]);
    }
    __syncthreads();
    cur ^= 1;
  }

  if constexpr (MODE == 0) {
#pragma unroll
    for (int ni = 0; ni < 4; ni++) {
      const int col = n0 + wc * 64 + ni * 16 + c;
#pragma unroll
      for (int mi = 0; mi < 4; mi++)
#pragma unroll
        for (int r = 0; r < 4; r++) {
          const int row = m0 + wr * 64 + mi * 16 + 4 * g + r;
          C[(size_t)row * N + col] = acc[mi][ni][r];
        }
    }
  } else {
    // ---- fused epilogue: acc+bias -> LDS bf16 [128][136], then RoPE/pack
    __bf16* sm = smem;
#pragma unroll
    for (int ni = 0; ni < 4; ni++) {
      const int col = wc * 64 + ni * 16 + c;
      const float bv = bias[n0 + col];
#pragma unroll
      for (int mi = 0; mi < 4; mi++)
#pragma unroll
        for (int r = 0; r < 4; r++)
          sm[(wr * 64 + mi * 16 + 4 * g + r) * 136 + col] =
              (__bf16)(acc[mi][ni][r] + bv);
    }
    __syncthreads();

    if (n0 < (NH + NKV) * HD) {  // Q or K head: RoPE
      const bool isq = n0 < NH * HD;
      // Q scale: 1/sqrt(128) * log2(e)  (exp2-domain softmax)
      const float sc = isq ? (0.08838834764831845f * 1.4426950408889634f) : 1.0f;
      __bf16* base = isq ? (Qp + (size_t)(n0 >> 7) * T_TOK * HD)
                         : (Kp + (size_t)((n0 >> 7) - NH) * T_TOK * HD);
#pragma unroll
      for (int jj = 0; jj < 4; jj++) {
        const int e = jj * 256 + tid;  // 128 t x 8 chunks of 8
        const int tl = e >> 3, ch = e & 7;
        const int tt = m0 + tl;
        const bf16x8 x1 = *(const bf16x8*)(sm + tl * 136 + ch * 8);
        const bf16x8 x2 = *(const bf16x8*)(sm + tl * 136 + 64 + ch * 8);
        const float4 c0 = *(const float4*)(cosT + tt * 64 + ch * 8);
        const float4 c1 = *(const float4*)(cosT + tt * 64 + ch * 8 + 4);
        const float4 s0 = *(const float4*)(sinT + tt * 64 + ch * 8);
        const float4 s1 = *(const float4*)(sinT + tt * 64 + ch * 8 + 4);
        const float cs[8] = {c0.x, c0.y, c0.z, c0.w, c1.x, c1.y, c1.z, c1.w};
        const float sn[8] = {s0.x, s0.y, s0.z, s0.w, s1.x, s1.y, s1.z, s1.w};
        bf16x8 o1, o2;
#pragma unroll
        for (int i = 0; i < 8; i++) {
          const float a = (float)x1[i], b = (float)x2[i];
          o1[i] = (__bf16)((a * cs[i] - b * sn[i]) * sc);
          o2[i] = (__bf16)((b * cs[i] + a * sn[i]) * sc);
        }
        const int d2s = isq ? ch * 8 : ((ch * 8) ^ ((tt & 7) << 3));
        __bf16* dst = base + (size_t)tt * HD;
        *(bf16x8*)(dst + d2s) = o1;
        *(bf16x8*)(dst + 64 + d2s) = o2;
      }
    } else {  // V head: fragment-pack two 64-token subtiles
      const int kv = (n0 >> 7) - (NH + NKV);
#pragma unroll
      for (int st2 = 0; st2 < 2; st2++) {
        __bf16* outb = Vf + ((size_t)kv * 64 + (m0 >> 6) + st2) * 8192;
#pragma unroll
        for (int jj = 0; jj < 4; jj++) {
          const int u = jj * 256 + tid;
          const int lu = u & 63, ks = (u >> 6) & 3, mq = u >> 8;
          const int d = mq * 32 + (lu & 31);
          const int tb = st2 * 64 + ks * 16 + ((lu >> 5) << 3);
          bf16x8 o;
#pragma unroll
          for (int jz = 0; jz < 8; jz++) o[jz] = sm[(tb + jz) * 136 + d];
          *(bf16x8*)(outb + (size_t)u * 8) = o;
        }
      }
    }
  }
}

// ---------------- flash attention (R14 verbatim): 32x32 MFMA, in-reg P,
// K-LDS dbuf, frag-packed V from global, kvh->XCD affinity map ----------------
__global__ __launch_bounds__(256, 2) void k_attn(const __bf16* __restrict__ Qp,
                                                 const __bf16* __restrict__ Kp,
                                                 const __bf16* __restrict__ Vf,
                                                 __bf16* __restrict__ attnO) {
  __shared__ __align__(16) __bf16 Ks[2][64 * 128];  // [buf][key][d] 256B rows

  const int tid = threadIdx.x;
  const int lane = tid & 63;
  const int w = tid >> 6;      // 0..3
  const int l31 = lane & 31;
  const int hi = lane >> 5;    // 0/1
  const int swz = (lane & 7) << 4;
  // bijective decode: xcd = bid&7 hosts heads {4*(xcd>>1) + 2*(xcd&1) + 0/1}
  const int bid = blockIdx.x;
  const int xcd = bid & 7, j = bid >> 3;
  const int h = ((xcd >> 1) << 2) + ((xcd & 1) << 1) + (j & 1);
  const int qb = 31 - (j >> 1);  // heavy blocks first
  const int kvh = h >> 2;
  const int q0 = qb * 128;
  const int iw = q0 + 32 * w;       // wave's first q row
  const int irow = iw + l31;        // this lane's q row

  // Q B-frags: col=q(=l31), k-step ds covers d=16ds+8hi+j
  bf16x8 qf[8];
  {
    const __bf16* qbase = Qp + ((size_t)h * T_TOK + irow) * HD;
#pragma unroll
    for (int ds = 0; ds < 8; ds++)
      qf[ds] = *(const bf16x8*)(qbase + ds * 16 + hi * 8);
  }

  f32x16 ot[4] = {};  // O^T: ot[m][reg] -> d=32m+(reg&3)+8*(reg>>2)+4hi, q=l31
  float mrun = 0.0f, lrun = 0.0f;  // exp2-domain, max-floor 0

  const int jstart = (q0 >= WIN) ? (q0 - WIN) : 0;
  const int niter = (q0 + 128 - jstart) >> 6;

  // K staging: wave w stages K rows [16w,16w+16)
  const char* Kg = (const char*)Kp + (size_t)kvh * T_TOK * HD * 2;
  const char* kg0 = Kg + (size_t)(jstart + 16 * w + (lane >> 4)) * 256 + (lane & 15) * 16;
  const __bf16* Vgb = Vf + (size_t)kvh * 64 * 8192;  // frag-packed tiles

#pragma unroll
  for (int q = 0; q < 4; q++)
    gload16(kg0 + q * 1024, (char*)&Ks[0][0] + w * 4096 + q * 1024);

  int cur = 0;

  for (int it = 0; it < niter; ++it) {
    const int j0 = jstart + it * 64;
    __syncthreads();  // K[cur] staged; everyone done reading K[cur^1]

    if (it + 1 < niter) {  // prefetch next K tile into buf cur^1
      const char* kg = kg0 + (size_t)(it + 1) * 16384;
      char* kd = (char*)&Ks[cur ^ 1][0] + w * 4096;
#pragma unroll
      for (int q = 0; q < 4; q++) gload16(kg + q * 1024, kd + q * 1024);
    }

    // wave-uniform relevance: skip tiles fully ahead of causal edge or
    // fully behind the window for ALL 32 of this wave's rows
    if (j0 > iw + 31) { cur ^= 1; continue; }          // all j > all i
    if (iw - (j0 + 63) > WIN) { cur ^= 1; continue; }  // all i-j > WIN

    // ---- issue V fragment loads EARLY (coalesced; covered by QK+softmax)
    const __bf16* vt = Vgb + (size_t)(j0 >> 6) * 8192;
    bf16x8 vf[4][4];
#pragma unroll
    for (int m = 0; m < 4; m++)
#pragma unroll
      for (int ks = 0; ks < 4; ks++)
        vf[m][ks] = *(const bf16x8*)(vt + (m * 256 + ks * 64 + lane) * 8);

    const char* kb = (const char*)&Ks[cur][0];

    // ---- S^T = K * Q^T : 2 key-subtiles x 8 k-steps of 32x32x16
    f32x16 st[2] = {};
    __builtin_amdgcn_s_setprio(1);
#pragma unroll
    for (int t = 0; t < 2; t++)
#pragma unroll
      for (int ds = 0; ds < 8; ds++) {
        bf16x8 kf = *(const bf16x8*)(kb + (t * 32 + l31) * 256 +
                                     ((ds * 32 + hi * 16) ^ swz));
        st[t] = mfma32(kf, qf[ds], st[t]);
      }
    __builtin_amdgcn_s_setprio(0);

    // ---- mask + online softmax; q=l31 lane-local.
    // key j = j0 + 32t + (reg&3) + 8*(reg>>2) + 4*hi
    float p[2][16];
    float cmax = -1e30f;
    const bool interior = (j0 + 63 <= iw) && (iw + 31 - j0 <= WIN);
    if (interior) {
#pragma unroll
      for (int t = 0; t < 2; t++)
#pragma unroll
        for (int r = 0; r < 16; r++) {
          const float s = st[t][r];
          p[t][r] = s;
          cmax = fmaxf(cmax, s);
        }
    } else {
      const int jb = irow - j0 - 4 * hi;  // i-j = jb - 32t - (r&3) - 8*(r>>2)
#pragma unroll
      for (int t = 0; t < 2; t++)
#pragma unroll
        for (int r = 0; r < 16; r++) {
          float s = st[t][r];
          const int off = 32 * t + (r & 3) + 8 * (r >> 2);
          s = ((unsigned)(jb - off) <= WIN) ? s : -1e30f;
          p[t][r] = s;
          cmax = fmaxf(cmax, s);
        }
    }
    cmax = fmaxf(cmax, __shfl_xor(cmax, 32));  // partner holds other keys

    // defer-max (T13): THR = 8*log2e
    if (!__all(cmax <= mrun + 11.54f)) {
      const float mn = fmaxf(mrun, cmax);
      const float alpha = exp2f(mrun - mn);
      lrun *= alpha;
#pragma unroll
      for (int m = 0; m < 4; m++) ot[m] *= alpha;
      mrun = mn;
    }
    float rs = 0.0f;
#pragma unroll
    for (int t = 0; t < 2; t++)
#pragma unroll
      for (int r = 0; r < 16; r++) {
        const float e_ = exp2f(p[t][r] - mrun);
        p[t][r] = e_;
        rs += e_;
      }
    rs += __shfl_xor(rs, 32);
    lrun += rs;

    // ---- P -> PV B-frags in-register (cvt_pk + permlane32_swap, T12)
    bf16x8 pb[4];
#pragma unroll
    for (int t = 0; t < 2; t++) {
      unsigned wds[8];
#pragma unroll
      for (int i = 0; i < 8; i++) wds[i] = cvtpk(p[t][2 * i], p[t][2 * i + 1]);
      pl32swap(wds[0], wds[2]);
      pl32swap(wds[1], wds[3]);
      pl32swap(wds[4], wds[6]);
      pl32swap(wds[5], wds[7]);
      u32x4 f0 = {wds[0], wds[1], wds[2], wds[3]};
      u32x4 f1 = {wds[4], wds[5], wds[6], wds[7]};
      pb[2 * t] = __builtin_bit_cast(bf16x8, f0);
      pb[2 * t + 1] = __builtin_bit_cast(bf16x8, f1);
    }

    // ---- O^T += V^T * P^T : 4 d-subtiles x 4 key-steps of 32x32x16
    __builtin_amdgcn_s_setprio(1);
#pragma unroll
    for (int m = 0; m < 4; m++)
#pragma unroll
      for (int ks = 0; ks < 4; ks++)
        ot[m] = mfma32(vf[m][ks], pb[ks], ot[m]);
    __builtin_amdgcn_s_setprio(0);

    cur ^= 1;
  }

  const float inv_l = 1.0f / lrun;
  __bf16* orow = attnO + (size_t)irow * (NH * HD) + h * HD;
#pragma unroll
  for (int m = 0; m < 4; m++)
#pragma unroll
    for (int rg = 0; rg < 4; rg++) {
      const int d0 = 32 * m + 8 * rg + 4 * hi;
      bf16x4 o4;
#pragma unroll
      for (int r = 0; r < 4; r++) o4[r] = (__bf16)(ot[m][4 * rg + r] * inv_l);
      *(bf16x4*)(orow + d0) = o4;
    }
}

// ---------------- launcher ----------------
extern "C" void kernel_launch(void* const* d_in, const int* in_sizes, int n_in,
                              void* d_out, int out_size, void* d_ws, size_t ws_size,
                              hipStream_t stream) {
  (void)in_sizes; (void)n_in; (void)out_size; (void)ws_size;
  const float* hidden = (const float*)d_in[0];
  const int* positions = (const int*)d_in[1];
  const float* w_qkv = (const float*)d_in[2];
  const float* b_qkv = (const float*)d_in[3];
  const float* w_o = (const float*)d_in[4];
  float* out = (float*)d_out;

  char* ws = (char*)d_ws;
  __bf16* Hb = (__bf16*)ws;    ws += (size_t)T_TOK * HID * 2;
  __bf16* Wqkvt = (__bf16*)ws; ws += (size_t)QKVO * HID * 2;
  __bf16* Wot = (__bf16*)ws;   ws += (size_t)HID * HID * 2;
  float* cosT = (float*)ws;    ws += (size_t)T_TOK * 64 * 4;
  float* sinT = (float*)ws;    ws += (size_t)T_TOK * 64 * 4;
  __bf16* Qp = (__bf16*)ws;    ws += (size_t)NH * T_TOK * HD * 2;
  __bf16* Kp = (__bf16*)ws;    ws += (size_t)NKV * T_TOK * HD * 2;
  __bf16* Vfb = (__bf16*)ws;   ws += (size_t)NKV * 64 * 8192 * 2;   // frag-packed V
  __bf16* attnb = (__bf16*)ws; ws += (size_t)T_TOK * NH * HD * 2;

  k_prep<<<7680, 256, 0, stream>>>(hidden, Hb, w_qkv, Wqkvt, w_o, Wot,
                                   positions, cosT, sinT);
  k_gemm<1><<<(T_TOK / 128) * (QKVO / 128), 256, 0, stream>>>(
      Hb, Wqkvt, b_qkv, nullptr, cosT, sinT, Qp, Kp, Vfb, T_TOK, QKVO, HID);
  k_attn<<<512, 256, 0, stream>>>(Qp, Kp, Vfb, attnb);
  k_gemm<0><<<(T_TOK / 128) * (HID / 128), 256, 0, stream>>>(
      attnb, Wot, nullptr, out, nullptr, nullptr, nullptr, nullptr, nullptr,
      T_TOK, HID, HID);
}